// Round 3
// baseline (256.306 us; speedup 1.0000x reference)
//
#include <hip/hip_runtime.h>
#include <math.h>

// B=32, Cin=64, H=W=56, Cout=128, K=3 pad=1 -> D=576, out (32,128,56,56) fp32
#define B_    32
#define CIN   64
#define HH    56
#define WW    56
#define COUT  128
#define DD    576
#define KC    384            // OpenBLAS kc split (verified R9)
#define LPX   (HH*WW)        // 3136 = 49*64
#define TOTAL (B_*COUT*LPX)
#define NX    (B_*CIN*LPX)   // 6422528
#define PW    58             // padded plane width/height
#define PPL   (PW*PW)        // 3364 words per padded channel plane
#define NXP   (B_*CIN*PPL)   // 6889472 words
#define MARGIN 4e-4f         // worst-case split-bf16 + reorder bound (validated R15-18)

typedef __attribute__((ext_vector_type(8)))  short  short8;
typedef __attribute__((ext_vector_type(16))) float  float16v;

__device__ __forceinline__ unsigned short bf16_rne(float f) {
    unsigned u = __float_as_uint(f);
    unsigned r = u + 0x7FFFu + ((u >> 16) & 1u);
    return (unsigned short)(r >> 16);
}
__device__ __forceinline__ float bf16_to_f(unsigned short h) {
    return __uint_as_float(((unsigned)h) << 16);
}

// ---- bit-exact numpy FLOAT_sin (npyv FMA path) — verified R9 ----
__device__ __forceinline__ float np_sinf(float x) {
#pragma clang fp contract(off)
    const float rint_cvt = 0x1.8p+23f;
    float q = __fmul_rn(x, 0x1.45f306p-1f);
    q = __fadd_rn(q, rint_cvt);
    q = __fsub_rn(q, rint_cvt);
    float r = fmaf(q, -0x1.921fb0p+0f, x);
    r = fmaf(q, -0x1.5110b4p-22f, r);
    r = fmaf(q, -0x1.846988p-48f, r);
    float r2 = __fmul_rn(r, r);
    float s = fmaf(0x1.7d3bbcp-19f, r2, -0x1.a06bbap-13f);
    s = fmaf(s, r2, 0x1.11119ap-7f);
    s = fmaf(s, r2, -0x1.555556p-3f);
    s = __fmul_rn(s, r2);
    s = fmaf(s, r, r);
    float c = fmaf(0x1.98e616p-16f, r2, -0x1.6c06dcp-10f);
    c = fmaf(c, r2, 0x1.55553cp-5f);
    c = fmaf(c, r2, -0.5f);
    c = fmaf(c, r2, 1.0f);
    int iq = (int)q;
    float res = (iq & 1) ? c : s;
    unsigned sgn = ((unsigned)(iq & 2)) << 30;
    return __uint_as_float(__float_as_uint(res) ^ sgn);
}
__device__ __forceinline__ int dec_np(float z) {
    float s = np_sinf(z);
    return (__fmul_rn(s, s) > 0.5f) ? 1 : 0;
}

// ---- merged prep: W -> fragment-major bf16 hi/lo pack (same layout as R2),
// x -> padded 58x58 planes of (hi | lo<<16) u32 words, borders zero ----
// W dst for (o,k): k18=k/32, kr=k%32, s=kr/16, half=(kr%16)/8, j=kr%8
//   lane = half*32 + (o%32), ot = o/32
//   idx  = (((k18*4 + ot)*2 + s)*64 + lane)*8 + j
__global__ __launch_bounds__(256)
void prep_all(const float* __restrict__ x, const float* __restrict__ W,
              unsigned* __restrict__ xpad,
              unsigned short* __restrict__ Wph, unsigned short* __restrict__ Wpl,
              unsigned* __restrict__ wcount) {
    int i = blockIdx.x * 256 + threadIdx.x;
    if (i == 0) *wcount = 0;
    if (i < COUT * DD) {
        int o = i / DD, k = i - o * DD;
        float w = W[i];
        unsigned short h = bf16_rne(w);
        unsigned short l = bf16_rne(w - bf16_to_f(h));
        int k18 = k >> 5, kr = k & 31;
        int s = (kr >> 4) & 1, half = (kr >> 3) & 1, j = kr & 7;
        int lane = half * 32 + (o & 31);
        int ot = o >> 5;
        unsigned dst = ((((unsigned)(k18 * 4 + ot)) * 2 + s) * 64 + lane) * 8 + j;
        Wph[dst] = h;
        Wpl[dst] = l;
    }
    if (i < NXP) {
        int bc = i / PPL;
        int r  = i - bc * PPL;
        int yy = r / PW;
        int xx = r - yy * PW;
        unsigned v = 0u;
        if (yy >= 1 && yy <= HH && xx >= 1 && xx <= WW) {
            float f = x[(size_t)bc * LPX + (yy - 1) * WW + (xx - 1)];
            unsigned short h = bf16_rne(f);
            unsigned short l = bf16_rne(f - bf16_to_f(h));
            v = (unsigned)h | ((unsigned)l << 16);
        }
        xpad[i] = v;
    }
}

// ---- MFMA conv: LDS-free, barrier-free, 1 wave per block.
// Each lane gathers its own B-fragment words directly from padded x:
// word(d, px) = xb[pxoff + DBASE(d)], DBASE compile-time via full unroll.
// v_perm repack -> Bh/Bl. Same 12-MFMA/step order as R2 -> bit-identical acc.
#define DBASE(d) ((unsigned)((((d) / 9) * PPL) + ((((d) % 9) / 3) * PW) + (((d) % 9) % 3)))

__global__ __launch_bounds__(64, 4)
void conv_mfma(const unsigned* __restrict__ xpad,
               const unsigned short* __restrict__ Wph,
               const unsigned short* __restrict__ Wpl,
               const float* __restrict__ bias,
               float* __restrict__ out,
               unsigned* __restrict__ wcount,
               unsigned* __restrict__ wlist,
               unsigned wcap) {
    const int lane = threadIdx.x;        // block = 1 wave (64)
    const int lm   = lane & 31;
    const int half = lane >> 5;
    const int pt   = blockIdx.x >> 2;
    const int wq   = blockIdx.x & 3;
    const int aw   = wq >> 1;
    const int nw   = wq & 1;
    const int b    = blockIdx.y;

    const int pxg = pt * 64 + nw * 32 + lm;
    const int ypx = pxg / WW;
    const int xpx = pxg - ypx * WW;
    const unsigned pxoff = (unsigned)(ypx * PW + xpx);

    const unsigned* xb = xpad + (size_t)b * (CIN * PPL);
    const uint4* wAh = (const uint4*)Wph + aw * 256 + lane;
    const uint4* wAl = (const uint4*)Wpl + aw * 256 + lane;

    float16v acc[2];
#pragma unroll
    for (int a = 0; a < 2; ++a)
#pragma unroll
        for (int i = 0; i < 16; ++i) acc[a][i] = 0.f;

    unsigned wB[2][8];     // 16 B-words for current step (s, j)
    uint4 Ah[2][2], Al[2][2];

#define LOADB(IT)                                                              \
    _Pragma("unroll") for (int s = 0; s < 2; ++s)                              \
    _Pragma("unroll") for (int j = 0; j < 8; ++j) {                            \
        const unsigned bb0 = DBASE((IT) * 32 + s * 16 + j);                    \
        const unsigned bb1 = DBASE((IT) * 32 + s * 16 + j + 8);                \
        unsigned db = half ? bb1 : bb0;                                        \
        wB[s][j] = xb[pxoff + db];                                             \
    }

#define LOADA(IT)                                                              \
    _Pragma("unroll") for (int a = 0; a < 2; ++a)                              \
    _Pragma("unroll") for (int s = 0; s < 2; ++s) {                            \
        Ah[a][s] = wAh[(IT) * 512 + a * 128 + s * 64];                         \
        Al[a][s] = wAl[(IT) * 512 + a * 128 + s * 64];                         \
    }

    LOADB(0)
    LOADA(0)

#pragma unroll
    for (int it = 0; it < 18; ++it) {
        // repack current B words into fragments (consumes wB)
        short8 Bh[2], Bl[2];
#pragma unroll
        for (int s = 0; s < 2; ++s)
#pragma unroll
            for (int m = 0; m < 4; ++m) {
                ((unsigned*)&Bh[s])[m] = __builtin_amdgcn_perm(
                    wB[s][2 * m + 1], wB[s][2 * m], 0x05040100u);
                ((unsigned*)&Bl[s])[m] = __builtin_amdgcn_perm(
                    wB[s][2 * m + 1], wB[s][2 * m], 0x07060302u);
            }

        // issue next step's B gathers into the freed wB regs (fly under MFMAs)
        if (it < 17) { LOADB(it + 1) }

#pragma unroll
        for (int s = 0; s < 2; ++s) {
#pragma unroll
            for (int a = 0; a < 2; ++a)
                acc[a] = __builtin_amdgcn_mfma_f32_32x32x16_bf16(
                    *(const short8*)&Ah[a][s], Bh[s], acc[a], 0, 0, 0);
#pragma unroll
            for (int a = 0; a < 2; ++a)
                acc[a] = __builtin_amdgcn_mfma_f32_32x32x16_bf16(
                    *(const short8*)&Ah[a][s], Bl[s], acc[a], 0, 0, 0);
#pragma unroll
            for (int a = 0; a < 2; ++a)
                acc[a] = __builtin_amdgcn_mfma_f32_32x32x16_bf16(
                    *(const short8*)&Al[a][s], Bh[s], acc[a], 0, 0, 0);
        }

        // reload A for next step into the just-consumed regs
        if (it < 17) { LOADA(it + 1) }
    }
#undef LOADB
#undef LOADA

    const size_t outb = (size_t)b * COUT * LPX;
#pragma unroll
    for (int a = 0; a < 2; ++a) {
        const int obase = aw * 64 + a * 32 + 4 * half;
#pragma unroll
        for (int reg = 0; reg < 16; ++reg) {
            int o = obase + (reg & 3) + 8 * (reg >> 2);
            float z = acc[a][reg] + bias[o];
            float q = rintf(__fmul_rn(z, 0.63661975f));
            float rr = fmaf(q, -1.5707964f, z);
            float d = fabsf(fabsf(rr) - 0.78539816f);
            size_t oidx = outb + (size_t)o * LPX + pxg;
            out[oidx] = (float)(((int)q) & 1);
            if (d < MARGIN) {
                unsigned pos = atomicAdd(wcount, 1u);
                if (pos < wcap) wlist[pos] = (unsigned)oidx;
            }
        }
    }
}

// ---- wave-cooperative fixup: 1 wave per 4 elements. Lanes gather (parallel,
// BW-bound); lanes 0-3 run the bit-exact kc=384-split serial FMA chain from
// LDS (order identical to R9 -> bit-identical z). ----
__global__ __launch_bounds__(64)
void exact_fix_wave(const float* __restrict__ x,
                    const float* __restrict__ Wt,
                    const float* __restrict__ bias,
                    float* __restrict__ out,
                    const unsigned* __restrict__ wcount,
                    const unsigned* __restrict__ wlist,
                    unsigned wcap) {
#pragma clang fp contract(off)
    __shared__ float sx[4][DD];
    __shared__ float sw[4][DD];
    const int lane = threadIdx.x;        // block = 1 wave
    unsigned n = *wcount;
    if (n > wcap) n = wcap;

    for (unsigned e0 = blockIdx.x * 4; e0 < n; e0 += gridDim.x * 4) {
        // gather 4 elements: lane = channel c
        unsigned idxs[4];
#pragma unroll
        for (int j = 0; j < 4; ++j) {
            unsigned e = e0 + j;
            if (e >= n) { idxs[j] = 0xFFFFFFFFu; continue; }
            unsigned idx = wlist[e];
            idxs[j] = idx;
            int px = idx % WW;
            unsigned t = idx / WW;
            int py = t % HH;  t /= HH;
            int o  = t % COUT;
            int b  = t / COUT;
            const float* xc = x  + ((size_t)(b * CIN + lane)) * LPX;
            const float* wc = Wt + (size_t)o * DD + lane * 9;
#pragma unroll
            for (int u = 0; u < 3; ++u)
#pragma unroll
                for (int v = 0; v < 3; ++v) {
                    int tp = u * 3 + v;
                    int gy = py + u - 1, gx = px + v - 1;
                    float p = ((unsigned)gy < HH && (unsigned)gx < WW)
                                  ? xc[gy * WW + gx] : 0.f;
                    sx[j][lane * 9 + tp] = p;
                    sw[j][lane * 9 + tp] = wc[tp];
                }
        }
        __syncthreads();
        if (lane < 4 && idxs[lane] != 0xFFFFFFFFu) {
            const float* px_ = sx[lane];
            const float* pw_ = sw[lane];
            float accA = 0.f, accB2 = 0.f;
            for (int d = 0; d < KC; ++d)        accA  = fmaf(px_[d], pw_[d], accA);
            for (int d = KC; d < DD; ++d)       accB2 = fmaf(px_[d], pw_[d], accB2);
            unsigned idx = idxs[lane];
            int o = (idx / LPX) % COUT;
            float zG = __fadd_rn(accA, accB2);
            float z  = __fadd_rn(zG, bias[o]);
            out[idx] = (float)dec_np(z);
        }
        __syncthreads();
    }
}

// ---- fallback (verified R9 path) ----
__global__ __launch_bounds__(256)
void np_emul_conv(const float* __restrict__ x,
                  const float* __restrict__ Wt,
                  const float* __restrict__ bias,
                  float* __restrict__ out) {
#pragma clang fp contract(off)
    int idx = blockIdx.x * 256 + threadIdx.x;
    if (idx >= TOTAL) return;
    int px = idx % WW;
    int t  = idx / WW;
    int py = t % HH;  t /= HH;
    int o  = t % COUT;
    int b  = t / COUT;
    const float* wrow = Wt + (size_t)o * DD;
    const float* xb   = x + (size_t)b * CIN * LPX;
    float accA = 0.f, accB2 = 0.f;
    for (int c = 0; c < CIN; ++c) {
        const float* xc = xb + c * LPX;
        const float* wc = wrow + c * 9;
        int dbase = c * 9;
#pragma unroll
        for (int u = 0; u < 3; ++u)
#pragma unroll
            for (int v = 0; v < 3; ++v) {
                int tp = u * 3 + v;
                int gy = py + u - 1, gx = px + v - 1;
                float p = ((unsigned)gy < HH && (unsigned)gx < WW) ? xc[gy * WW + gx] : 0.f;
                if (dbase + tp < KC) accA  = fmaf(p, wc[tp], accA);
                else                 accB2 = fmaf(p, wc[tp], accB2);
            }
    }
    float z = __fadd_rn(__fadd_rn(accA, accB2), bias[o]);
    out[idx] = (float)dec_np(z);
}

extern "C" void kernel_launch(void* const* d_in, const int* in_sizes, int n_in,
                              void* d_out, int out_size, void* d_ws, size_t ws_size,
                              hipStream_t stream) {
    const float* x  = (const float*)d_in[0];
    const float* Wt = (const float*)d_in[1];
    const float* bb = (const float*)d_in[2];
    float* out = (float*)d_out;

    const size_t WSPLIT = (size_t)COUT * DD * 2;          // 147456 B each
    const size_t XP     = (size_t)NXP * 4;                // 27.56 MB padded
    const size_t FIXED  = 2 * WSPLIT + XP + 4;

    if (ws_size >= FIXED + 65536) {
        unsigned short* Wph = (unsigned short*)d_ws;
        unsigned short* Wpl = Wph + COUT * DD;
        unsigned* xpad   = (unsigned*)((char*)d_ws + 2 * WSPLIT);
        unsigned* wcount = (unsigned*)((char*)d_ws + 2 * WSPLIT + XP);
        unsigned* wlist  = wcount + 1;
        size_t avail = (ws_size - FIXED) / 4;
        unsigned wcap = (avail > 2000000u) ? 2000000u : (unsigned)avail;

        prep_all<<<dim3(NXP / 256), dim3(256), 0, stream>>>(x, Wt, xpad, Wph, Wpl, wcount);
        conv_mfma<<<dim3(49 * 4, B_), dim3(64), 0, stream>>>(xpad, Wph, Wpl, bb, out,
                                                             wcount, wlist, wcap);
        exact_fix_wave<<<dim3(1024), dim3(64), 0, stream>>>(x, Wt, bb, out,
                                                            wcount, wlist, wcap);
    } else {
        np_emul_conv<<<(TOTAL + 255) / 256, 256, 0, stream>>>(x, Wt, bb, out);
    }
}

// Round 4
// 241.363 us; speedup vs baseline: 1.0619x; 1.0619x over previous
//
#include <hip/hip_runtime.h>
#include <math.h>

// B=32, Cin=64, H=W=56, Cout=128, K=3 pad=1 -> D=576, out (32,128,56,56) fp32
#define B_    32
#define CIN   64
#define HH    56
#define WW    56
#define COUT  128
#define DD    576
#define KC    384            // OpenBLAS kc split (verified R9)
#define LPX   (HH*WW)        // 3136 = 49*64
#define TOTAL (B_*COUT*LPX)
#define NX    (B_*CIN*LPX)   // 6422528
#define PW    58             // padded plane width/height
#define PPL   (PW*PW)        // 3364 words per padded channel plane
#define NXP   (B_*CIN*PPL)   // 6889472 words
#define MARGIN 4e-4f         // worst-case split-bf16 + reorder bound (validated R15-18)

typedef __attribute__((ext_vector_type(8)))  short  short8;
typedef __attribute__((ext_vector_type(16))) float  float16v;

__device__ __forceinline__ unsigned short bf16_rne(float f) {
    unsigned u = __float_as_uint(f);
    unsigned r = u + 0x7FFFu + ((u >> 16) & 1u);
    return (unsigned short)(r >> 16);
}
__device__ __forceinline__ float bf16_to_f(unsigned short h) {
    return __uint_as_float(((unsigned)h) << 16);
}

// ---- bit-exact numpy FLOAT_sin (npyv FMA path) — verified R9 ----
__device__ __forceinline__ float np_sinf(float x) {
#pragma clang fp contract(off)
    const float rint_cvt = 0x1.8p+23f;
    float q = __fmul_rn(x, 0x1.45f306p-1f);
    q = __fadd_rn(q, rint_cvt);
    q = __fsub_rn(q, rint_cvt);
    float r = fmaf(q, -0x1.921fb0p+0f, x);
    r = fmaf(q, -0x1.5110b4p-22f, r);
    r = fmaf(q, -0x1.846988p-48f, r);
    float r2 = __fmul_rn(r, r);
    float s = fmaf(0x1.7d3bbcp-19f, r2, -0x1.a06bbap-13f);
    s = fmaf(s, r2, 0x1.11119ap-7f);
    s = fmaf(s, r2, -0x1.555556p-3f);
    s = __fmul_rn(s, r2);
    s = fmaf(s, r, r);
    float c = fmaf(0x1.98e616p-16f, r2, -0x1.6c06dcp-10f);
    c = fmaf(c, r2, 0x1.55553cp-5f);
    c = fmaf(c, r2, -0.5f);
    c = fmaf(c, r2, 1.0f);
    int iq = (int)q;
    float res = (iq & 1) ? c : s;
    unsigned sgn = ((unsigned)(iq & 2)) << 30;
    return __uint_as_float(__float_as_uint(res) ^ sgn);
}
__device__ __forceinline__ int dec_np(float z) {
    float s = np_sinf(z);
    return (__fmul_rn(s, s) > 0.5f) ? 1 : 0;
}

// ---- merged prep: W -> fragment-major bf16 hi/lo pack, x -> padded 58x58
// planes of (hi | lo<<16) u32 words, borders zero (verified R3) ----
// W dst for (o,k): k18=k/32, kr=k%32, s=kr/16, half=(kr%16)/8, j=kr%8
//   lane = half*32 + (o%32), ot = o/32
//   idx  = (((k18*4 + ot)*2 + s)*64 + lane)*8 + j
__global__ __launch_bounds__(256)
void prep_all(const float* __restrict__ x, const float* __restrict__ W,
              unsigned* __restrict__ xpad,
              unsigned short* __restrict__ Wph, unsigned short* __restrict__ Wpl,
              unsigned* __restrict__ wcount) {
    int i = blockIdx.x * 256 + threadIdx.x;
    if (i == 0) *wcount = 0;
    if (i < COUT * DD) {
        int o = i / DD, k = i - o * DD;
        float w = W[i];
        unsigned short h = bf16_rne(w);
        unsigned short l = bf16_rne(w - bf16_to_f(h));
        int k18 = k >> 5, kr = k & 31;
        int s = (kr >> 4) & 1, half = (kr >> 3) & 1, j = kr & 7;
        int lane = half * 32 + (o & 31);
        int ot = o >> 5;
        unsigned dst = ((((unsigned)(k18 * 4 + ot)) * 2 + s) * 64 + lane) * 8 + j;
        Wph[dst] = h;
        Wpl[dst] = l;
    }
    if (i < NXP) {
        int bc = i / PPL;
        int r  = i - bc * PPL;
        int yy = r / PW;
        int xx = r - yy * PW;
        unsigned v = 0u;
        if (yy >= 1 && yy <= HH && xx >= 1 && xx <= WW) {
            float f = x[(size_t)bc * LPX + (yy - 1) * WW + (xx - 1)];
            unsigned short h = bf16_rne(f);
            unsigned short l = bf16_rne(f - bf16_to_f(h));
            v = (unsigned)h | ((unsigned)l << 16);
        }
        xpad[i] = v;
    }
}

// ---- MFMA conv: 128px x 128out tile, 256 threads (4 waves).
// Wave w owns o-block w*32..w*32+31 across all 4 pixel positions (n=0..3).
// A: direct global->reg from packed Wph/Wpl (L2-hot, zero duplication),
//    prefetched 1 step ahead. P: padded-gather -> regs -> dbuf LDS, one
//    barrier/step (dbuf WAR safety verified R2). Per-acc MFMA order
//    identical to R2 -> bit-identical acc -> MARGIN still valid.
#define FRAG(t, s, hf, ln)  (((t) * 1024) + ((s) * 512) + ((hf) * 256) + ((ln) * 8))
__global__ __launch_bounds__(256, 3)
void conv_mfma(const unsigned* __restrict__ xpad,
               const unsigned short* __restrict__ Wph,
               const unsigned short* __restrict__ Wpl,
               const float* __restrict__ bias,
               float* __restrict__ out,
               unsigned* __restrict__ wcount,
               unsigned* __restrict__ wlist,
               unsigned wcap) {
    __shared__ __align__(16) unsigned short sPh[2][4096];
    __shared__ __align__(16) unsigned short sPl[2][4096];

    const int tid = threadIdx.x;
    // XCD-chunked bijective swizzle (784 = 8*98): round-robin dispatch puts
    // orig%8==c on XCD c; map each XCD to a contiguous 98-block data chunk
    // (~4 batches, ~3.4MB xpad slice -> fits 4MB L2).
    const int bid = (blockIdx.x & 7) * 98 + (blockIdx.x >> 3);
    const int pt0 = bid * 128;

    const int plane = tid & 15;
    const int pair  = tid >> 4;
    const int s_st  = pair >> 3;
    const int h_st  = (pair >> 2) & 1;
    const int j2_st = pair & 3;

    // per-r pixel bases into padded x (b-uniform per 16-px group: LPX%16==0)
    unsigned pbase[8];
#pragma unroll
    for (int r = 0; r < 8; ++r) {
        int gp = pt0 + plane + r * 16;
        int br = gp / LPX;
        int pr = gp - br * LPX;
        int ypx = pr / WW;
        int xpx = pr - ypx * WW;
        pbase[r] = (unsigned)(br * (CIN * PPL) + ypx * PW + xpx);
    }

    const int w    = tid >> 6;           // o-tile (0..3)
    const int lane = tid & 63;
    const int lm   = lane & 31;
    const int half = lane >> 5;
    const uint4* wAh = (const uint4*)Wph + w * 128 + lane;
    const uint4* wAl = (const uint4*)Wpl + w * 128 + lane;

    float16v acc[4];
#pragma unroll
    for (int n = 0; n < 4; ++n)
#pragma unroll
        for (int i = 0; i < 16; ++i) acc[n][i] = 0.f;

    unsigned pg[8][2], pgn[8][2];
    uint4 Ah[2], Al[2], Ahn[2], Aln[2];

#define LOADP(K0, DST)                                                         \
    {                                                                          \
        int d0 = (K0) + pair * 2;                                              \
        int c0 = d0 / 9, t0 = d0 - c0 * 9;                                     \
        int u0 = t0 / 3, v0 = t0 - u0 * 3;                                     \
        int t1 = t0 + 1, c1 = c0;                                              \
        if (t1 == 9) { t1 = 0; c1 = c0 + 1; }                                  \
        int u1 = t1 / 3, v1 = t1 - u1 * 3;                                     \
        unsigned off0 = (unsigned)(c0 * PPL + u0 * PW + v0);                   \
        unsigned off1 = (unsigned)(c1 * PPL + u1 * PW + v1);                   \
        _Pragma("unroll")                                                      \
        for (int r = 0; r < 8; ++r) {                                          \
            DST[r][0] = xpad[pbase[r] + off0];                                 \
            DST[r][1] = xpad[pbase[r] + off1];                                 \
        }                                                                      \
    }

#define LOADA(IT, DH, DL)                                                      \
    _Pragma("unroll")                                                          \
    for (int s = 0; s < 2; ++s) {                                              \
        DH[s] = wAh[(IT) * 512 + s * 64];                                      \
        DL[s] = wAl[(IT) * 512 + s * 64];                                      \
    }

    LOADP(0, pg)
    LOADA(0, Ah, Al)

#pragma unroll
    for (int it = 0; it < 18; ++it) {
        unsigned short* bPh = sPh[it & 1];
        unsigned short* bPl = sPl[it & 1];

        // publish step it's patches (prefetched regs -> LDS)
#pragma unroll
        for (int r = 0; r < 8; ++r) {
            unsigned g0 = pg[r][0], g1 = pg[r][1];
            unsigned hw = (g0 & 0xFFFFu) | (g1 << 16);
            unsigned lw = (g0 >> 16) | (g1 & 0xFFFF0000u);
            int pm = plane + (r & 1) * 16;
            int word = (r >> 1) * 512 + s_st * 256 + h_st * 128 + pm * 4 + j2_st;
            ((unsigned*)bPh)[word] = hw;
            ((unsigned*)bPl)[word] = lw;
        }

        // issue next step's A + P loads; they land under the MFMA phase
        if (it < 17) {
            LOADA(it + 1, Ahn, Aln)
            LOADP((it + 1) * 32, pgn)
        }

        // drain own ds_writes, rendezvous; prefetch loads stay in flight
        asm volatile("s_waitcnt lgkmcnt(0)" ::: "memory");
        __builtin_amdgcn_s_barrier();
        asm volatile("" ::: "memory");

#pragma unroll
        for (int n = 0; n < 4; ++n) {
            short8 Bh0 = *(const short8*)(bPh + FRAG(n, 0, half, lm));
            short8 Bl0 = *(const short8*)(bPl + FRAG(n, 0, half, lm));
            short8 Bh1 = *(const short8*)(bPh + FRAG(n, 1, half, lm));
            short8 Bl1 = *(const short8*)(bPl + FRAG(n, 1, half, lm));
            acc[n] = __builtin_amdgcn_mfma_f32_32x32x16_bf16(
                *(const short8*)&Ah[0], Bh0, acc[n], 0, 0, 0);
            acc[n] = __builtin_amdgcn_mfma_f32_32x32x16_bf16(
                *(const short8*)&Ah[0], Bl0, acc[n], 0, 0, 0);
            acc[n] = __builtin_amdgcn_mfma_f32_32x32x16_bf16(
                *(const short8*)&Al[0], Bh0, acc[n], 0, 0, 0);
            acc[n] = __builtin_amdgcn_mfma_f32_32x32x16_bf16(
                *(const short8*)&Ah[1], Bh1, acc[n], 0, 0, 0);
            acc[n] = __builtin_amdgcn_mfma_f32_32x32x16_bf16(
                *(const short8*)&Ah[1], Bl1, acc[n], 0, 0, 0);
            acc[n] = __builtin_amdgcn_mfma_f32_32x32x16_bf16(
                *(const short8*)&Al[1], Bh1, acc[n], 0, 0, 0);
        }

        if (it < 17) {
#pragma unroll
            for (int r = 0; r < 8; ++r) {
                pg[r][0] = pgn[r][0];
                pg[r][1] = pgn[r][1];
            }
#pragma unroll
            for (int s = 0; s < 2; ++s) {
                Ah[s] = Ahn[s];
                Al[s] = Aln[s];
            }
        }
    }
#undef LOADP
#undef LOADA

#pragma unroll
    for (int n = 0; n < 4; ++n) {
        const int gp0 = pt0 + n * 32;
        const int bpos = gp0 / LPX;
        const int pxb = gp0 - bpos * LPX + lm;
        const size_t outb = (size_t)bpos * COUT * LPX;
#pragma unroll
        for (int reg = 0; reg < 16; ++reg) {
            int o = w * 32 + 4 * half + (reg & 3) + 8 * (reg >> 2);
            float z = acc[n][reg] + bias[o];
            float q = rintf(__fmul_rn(z, 0.63661975f));
            float rr = fmaf(q, -1.5707964f, z);
            float d = fabsf(fabsf(rr) - 0.78539816f);
            size_t oidx = outb + (size_t)o * LPX + pxb;
            out[oidx] = (float)(((int)q) & 1);
            if (d < MARGIN) {
                unsigned pos = atomicAdd(wcount, 1u);
                if (pos < wcap) wlist[pos] = (unsigned)oidx;
            }
        }
    }
}

// ---- wave-cooperative fixup: 1 wave per 4 elements. Lanes gather (parallel,
// BW-bound); lanes 0-3 run the bit-exact kc=384-split serial FMA chain from
// LDS (order identical to R9 -> bit-identical z). ----
__global__ __launch_bounds__(64)
void exact_fix_wave(const float* __restrict__ x,
                    const float* __restrict__ Wt,
                    const float* __restrict__ bias,
                    float* __restrict__ out,
                    const unsigned* __restrict__ wcount,
                    const unsigned* __restrict__ wlist,
                    unsigned wcap) {
#pragma clang fp contract(off)
    __shared__ float sx[4][DD];
    __shared__ float sw[4][DD];
    const int lane = threadIdx.x;        // block = 1 wave
    unsigned n = *wcount;
    if (n > wcap) n = wcap;

    for (unsigned e0 = blockIdx.x * 4; e0 < n; e0 += gridDim.x * 4) {
        // gather 4 elements: lane = channel c
        unsigned idxs[4];
#pragma unroll
        for (int j = 0; j < 4; ++j) {
            unsigned e = e0 + j;
            if (e >= n) { idxs[j] = 0xFFFFFFFFu; continue; }
            unsigned idx = wlist[e];
            idxs[j] = idx;
            int px = idx % WW;
            unsigned t = idx / WW;
            int py = t % HH;  t /= HH;
            int o  = t % COUT;
            int b  = t / COUT;
            const float* xc = x  + ((size_t)(b * CIN + lane)) * LPX;
            const float* wc = Wt + (size_t)o * DD + lane * 9;
#pragma unroll
            for (int u = 0; u < 3; ++u)
#pragma unroll
                for (int v = 0; v < 3; ++v) {
                    int tp = u * 3 + v;
                    int gy = py + u - 1, gx = px + v - 1;
                    float p = ((unsigned)gy < HH && (unsigned)gx < WW)
                                  ? xc[gy * WW + gx] : 0.f;
                    sx[j][lane * 9 + tp] = p;
                    sw[j][lane * 9 + tp] = wc[tp];
                }
        }
        __syncthreads();
        if (lane < 4 && idxs[lane] != 0xFFFFFFFFu) {
            const float* px_ = sx[lane];
            const float* pw_ = sw[lane];
            float accA = 0.f, accB2 = 0.f;
            for (int d = 0; d < KC; ++d)        accA  = fmaf(px_[d], pw_[d], accA);
            for (int d = KC; d < DD; ++d)       accB2 = fmaf(px_[d], pw_[d], accB2);
            unsigned idx = idxs[lane];
            int o = (idx / LPX) % COUT;
            float zG = __fadd_rn(accA, accB2);
            float z  = __fadd_rn(zG, bias[o]);
            out[idx] = (float)dec_np(z);
        }
        __syncthreads();
    }
}

// ---- fallback (verified R9 path) ----
__global__ __launch_bounds__(256)
void np_emul_conv(const float* __restrict__ x,
                  const float* __restrict__ Wt,
                  const float* __restrict__ bias,
                  float* __restrict__ out) {
#pragma clang fp contract(off)
    int idx = blockIdx.x * 256 + threadIdx.x;
    if (idx >= TOTAL) return;
    int px = idx % WW;
    int t  = idx / WW;
    int py = t % HH;  t /= HH;
    int o  = t % COUT;
    int b  = t / COUT;
    const float* wrow = Wt + (size_t)o * DD;
    const float* xb   = x + (size_t)b * CIN * LPX;
    float accA = 0.f, accB2 = 0.f;
    for (int c = 0; c < CIN; ++c) {
        const float* xc = xb + c * LPX;
        const float* wc = wrow + c * 9;
        int dbase = c * 9;
#pragma unroll
        for (int u = 0; u < 3; ++u)
#pragma unroll
            for (int v = 0; v < 3; ++v) {
                int tp = u * 3 + v;
                int gy = py + u - 1, gx = px + v - 1;
                float p = ((unsigned)gy < HH && (unsigned)gx < WW) ? xc[gy * WW + gx] : 0.f;
                if (dbase + tp < KC) accA  = fmaf(p, wc[tp], accA);
                else                 accB2 = fmaf(p, wc[tp], accB2);
            }
    }
    float z = __fadd_rn(__fadd_rn(accA, accB2), bias[o]);
    out[idx] = (float)dec_np(z);
}

extern "C" void kernel_launch(void* const* d_in, const int* in_sizes, int n_in,
                              void* d_out, int out_size, void* d_ws, size_t ws_size,
                              hipStream_t stream) {
    const float* x  = (const float*)d_in[0];
    const float* Wt = (const float*)d_in[1];
    const float* bb = (const float*)d_in[2];
    float* out = (float*)d_out;

    const size_t WSPLIT = (size_t)COUT * DD * 2;          // 147456 B each
    const size_t XP     = (size_t)NXP * 4;                // 27.56 MB padded
    const size_t FIXED  = 2 * WSPLIT + XP + 4;

    if (ws_size >= FIXED + 65536) {
        unsigned short* Wph = (unsigned short*)d_ws;
        unsigned short* Wpl = Wph + COUT * DD;
        unsigned* xpad   = (unsigned*)((char*)d_ws + 2 * WSPLIT);
        unsigned* wcount = (unsigned*)((char*)d_ws + 2 * WSPLIT + XP);
        unsigned* wlist  = wcount + 1;
        size_t avail = (ws_size - FIXED) / 4;
        unsigned wcap = (avail > 2000000u) ? 2000000u : (unsigned)avail;

        prep_all<<<dim3(NXP / 256), dim3(256), 0, stream>>>(x, Wt, xpad, Wph, Wpl, wcount);
        conv_mfma<<<dim3(784), dim3(256), 0, stream>>>(xpad, Wph, Wpl, bb, out,
                                                       wcount, wlist, wcap);
        exact_fix_wave<<<dim3(1024), dim3(64), 0, stream>>>(x, Wt, bb, out,
                                                            wcount, wlist, wcap);
    } else {
        np_emul_conv<<<(TOTAL + 255) / 256, 256, 0, stream>>>(x, Wt, bb, out);
    }
}

// Round 5
// 218.770 us; speedup vs baseline: 1.1716x; 1.1033x over previous
//
#include <hip/hip_runtime.h>
#include <math.h>

// B=32, Cin=64, H=W=56, Cout=128, K=3 pad=1 -> D=576, out (32,128,56,56) fp32
#define B_    32
#define CIN   64
#define HH    56
#define WW    56
#define COUT  128
#define DD    576
#define KC    384            // OpenBLAS kc split (verified R9)
#define LPX   (HH*WW)        // 3136 = 49*64
#define TOTAL (B_*COUT*LPX)
#define NX    (B_*CIN*LPX)   // 6422528
#define PW    58             // padded plane width/height
#define PPL   (PW*PW)        // 3364 words per padded channel plane
#define NXP   (B_*CIN*PPL)   // 6889472 words
#define MARGIN 4e-4f         // worst-case split-bf16 + reorder bound (validated R15-18)

typedef __attribute__((ext_vector_type(8)))  short  short8;
typedef __attribute__((ext_vector_type(16))) float  float16v;

__device__ __forceinline__ unsigned short bf16_rne(float f) {
    unsigned u = __float_as_uint(f);
    unsigned r = u + 0x7FFFu + ((u >> 16) & 1u);
    return (unsigned short)(r >> 16);
}
__device__ __forceinline__ float bf16_to_f(unsigned short h) {
    return __uint_as_float(((unsigned)h) << 16);
}

// ---- bit-exact numpy FLOAT_sin (npyv FMA path) — verified R9 ----
__device__ __forceinline__ float np_sinf(float x) {
#pragma clang fp contract(off)
    const float rint_cvt = 0x1.8p+23f;
    float q = __fmul_rn(x, 0x1.45f306p-1f);
    q = __fadd_rn(q, rint_cvt);
    q = __fsub_rn(q, rint_cvt);
    float r = fmaf(q, -0x1.921fb0p+0f, x);
    r = fmaf(q, -0x1.5110b4p-22f, r);
    r = fmaf(q, -0x1.846988p-48f, r);
    float r2 = __fmul_rn(r, r);
    float s = fmaf(0x1.7d3bbcp-19f, r2, -0x1.a06bbap-13f);
    s = fmaf(s, r2, 0x1.11119ap-7f);
    s = fmaf(s, r2, -0x1.555556p-3f);
    s = __fmul_rn(s, r2);
    s = fmaf(s, r, r);
    float c = fmaf(0x1.98e616p-16f, r2, -0x1.6c06dcp-10f);
    c = fmaf(c, r2, 0x1.55553cp-5f);
    c = fmaf(c, r2, -0.5f);
    c = fmaf(c, r2, 1.0f);
    int iq = (int)q;
    float res = (iq & 1) ? c : s;
    unsigned sgn = ((unsigned)(iq & 2)) << 30;
    return __uint_as_float(__float_as_uint(res) ^ sgn);
}
__device__ __forceinline__ int dec_np(float z) {
    float s = np_sinf(z);
    return (__fmul_rn(s, s) > 0.5f) ? 1 : 0;
}

// ---- merged prep: W -> fragment-major bf16 hi/lo pack, x -> padded 58x58
// planes of (hi | lo<<16) u32 words, borders zero (verified R3/R4) ----
// W dst for (o,k): k18=k/32, kr=k%32, s=kr/16, half=(kr%16)/8, j=kr%8
//   lane = half*32 + (o%32), ot = o/32
//   idx  = (((k18*4 + ot)*2 + s)*64 + lane)*8 + j
__global__ __launch_bounds__(256)
void prep_all(const float* __restrict__ x, const float* __restrict__ W,
              unsigned* __restrict__ xpad,
              unsigned short* __restrict__ Wph, unsigned short* __restrict__ Wpl,
              unsigned* __restrict__ wcount) {
    int i = blockIdx.x * 256 + threadIdx.x;
    if (i == 0) *wcount = 0;
    if (i < COUT * DD) {
        int o = i / DD, k = i - o * DD;
        float w = W[i];
        unsigned short h = bf16_rne(w);
        unsigned short l = bf16_rne(w - bf16_to_f(h));
        int k18 = k >> 5, kr = k & 31;
        int s = (kr >> 4) & 1, half = (kr >> 3) & 1, j = kr & 7;
        int lane = half * 32 + (o & 31);
        int ot = o >> 5;
        unsigned dst = ((((unsigned)(k18 * 4 + ot)) * 2 + s) * 64 + lane) * 8 + j;
        Wph[dst] = h;
        Wpl[dst] = l;
    }
    if (i < NXP) {
        int bc = i / PPL;
        int r  = i - bc * PPL;
        int yy = r / PW;
        int xx = r - yy * PW;
        unsigned v = 0u;
        if (yy >= 1 && yy <= HH && xx >= 1 && xx <= WW) {
            float f = x[(size_t)bc * LPX + (yy - 1) * WW + (xx - 1)];
            unsigned short h = bf16_rne(f);
            unsigned short l = bf16_rne(f - bf16_to_f(h));
            v = (unsigned)h | ((unsigned)l << 16);
        }
        xpad[i] = v;
    }
}

// ---- MFMA conv: 64px x 128out tile, 256 threads (4 waves).
// Wave w owns o-block w*32..w*32+31 across both 32-px positions (n=0,1):
// acc[2] = 32 AGPRs -> ~100 unified regs -> 4 waves/SIMD, 4 blocks/CU.
// Grid 1568 = 8*196 (bijective XCD chunk = exactly 4 batches -> L2-fit);
// per-CU 6.125 blocks over 4 resident slots -> tail amortized (R4's 2x
// quantization tail was the bottleneck).
// A: direct global->reg from packed Wph/Wpl (L2-hot, zero duplication),
//    prefetched 1 step ahead. P: padded-gather -> regs -> dbuf LDS, one
//    barrier/step (dbuf WAR safety verified R2/R4). Per-acc MFMA order
//    identical to R2/R4 -> bit-identical acc -> MARGIN still valid.
#define FRAG(t, s, hf, ln)  (((t) * 1024) + ((s) * 512) + ((hf) * 256) + ((ln) * 8))
__global__ __launch_bounds__(256, 4)
void conv_mfma(const unsigned* __restrict__ xpad,
               const unsigned short* __restrict__ Wph,
               const unsigned short* __restrict__ Wpl,
               const float* __restrict__ bias,
               float* __restrict__ out,
               unsigned* __restrict__ wcount,
               unsigned* __restrict__ wlist,
               unsigned wcap) {
    __shared__ __align__(16) unsigned short sPh[2][2048];
    __shared__ __align__(16) unsigned short sPl[2][2048];

    const int tid = threadIdx.x;
    // XCD-chunked bijective swizzle (1568 = 8*196): round-robin dispatch puts
    // orig%8==c on XCD c; give each XCD a contiguous 196-block chunk
    // (= exactly 4 batches of xpad, ~3.4MB -> fits 4MB L2).
    const int bid = (blockIdx.x & 7) * 196 + (blockIdx.x >> 3);
    const int pt0 = bid * 64;            // 64-px tile, never crosses a batch

    const int plane = tid & 15;
    const int pair  = tid >> 4;
    const int s_st  = pair >> 3;
    const int h_st  = (pair >> 2) & 1;
    const int j2_st = pair & 3;

    // per-r pixel bases into padded x (b folded in; LPX%64==0 so b-uniform)
    unsigned pbase[4];
#pragma unroll
    for (int r = 0; r < 4; ++r) {
        int gp = pt0 + plane + r * 16;
        int br = gp / LPX;
        int pr = gp - br * LPX;
        int ypx = pr / WW;
        int xpx = pr - ypx * WW;
        pbase[r] = (unsigned)(br * (CIN * PPL) + ypx * PW + xpx);
    }

    const int w    = tid >> 6;           // o-tile (0..3)
    const int lane = tid & 63;
    const int lm   = lane & 31;
    const int half = lane >> 5;
    const uint4* wAh = (const uint4*)Wph + w * 128 + lane;
    const uint4* wAl = (const uint4*)Wpl + w * 128 + lane;

    float16v acc[2];
#pragma unroll
    for (int n = 0; n < 2; ++n)
#pragma unroll
        for (int i = 0; i < 16; ++i) acc[n][i] = 0.f;

    unsigned pg[4][2], pgn[4][2];
    uint4 Ah[2], Al[2], Ahn[2], Aln[2];

#define LOADP(K0, DST)                                                         \
    {                                                                          \
        int d0 = (K0) + pair * 2;                                              \
        int c0 = d0 / 9, t0 = d0 - c0 * 9;                                     \
        int u0 = t0 / 3, v0 = t0 - u0 * 3;                                     \
        int t1 = t0 + 1, c1 = c0;                                              \
        if (t1 == 9) { t1 = 0; c1 = c0 + 1; }                                  \
        int u1 = t1 / 3, v1 = t1 - u1 * 3;                                     \
        unsigned off0 = (unsigned)(c0 * PPL + u0 * PW + v0);                   \
        unsigned off1 = (unsigned)(c1 * PPL + u1 * PW + v1);                   \
        _Pragma("unroll")                                                      \
        for (int r = 0; r < 4; ++r) {                                          \
            DST[r][0] = xpad[pbase[r] + off0];                                 \
            DST[r][1] = xpad[pbase[r] + off1];                                 \
        }                                                                      \
    }

#define LOADA(IT, DH, DL)                                                      \
    _Pragma("unroll")                                                          \
    for (int s = 0; s < 2; ++s) {                                              \
        DH[s] = wAh[(IT) * 512 + s * 64];                                      \
        DL[s] = wAl[(IT) * 512 + s * 64];                                      \
    }

    LOADP(0, pg)
    LOADA(0, Ah, Al)

#pragma unroll
    for (int it = 0; it < 18; ++it) {
        unsigned short* bPh = sPh[it & 1];
        unsigned short* bPl = sPl[it & 1];

        // publish step it's patches (prefetched regs -> LDS)
#pragma unroll
        for (int r = 0; r < 4; ++r) {
            unsigned g0 = pg[r][0], g1 = pg[r][1];
            unsigned hw = (g0 & 0xFFFFu) | (g1 << 16);
            unsigned lw = (g0 >> 16) | (g1 & 0xFFFF0000u);
            int pm = plane + (r & 1) * 16;
            int word = (r >> 1) * 512 + s_st * 256 + h_st * 128 + pm * 4 + j2_st;
            ((unsigned*)bPh)[word] = hw;
            ((unsigned*)bPl)[word] = lw;
        }

        // issue next step's A + P loads; they land under the MFMA phase
        if (it < 17) {
            LOADA(it + 1, Ahn, Aln)
            LOADP((it + 1) * 32, pgn)
        }

        // drain own ds ops, rendezvous; prefetch loads stay in flight
        asm volatile("s_waitcnt lgkmcnt(0)" ::: "memory");
        __builtin_amdgcn_s_barrier();
        asm volatile("" ::: "memory");

#pragma unroll
        for (int n = 0; n < 2; ++n) {
            short8 Bh0 = *(const short8*)(bPh + FRAG(n, 0, half, lm));
            short8 Bl0 = *(const short8*)(bPl + FRAG(n, 0, half, lm));
            short8 Bh1 = *(const short8*)(bPh + FRAG(n, 1, half, lm));
            short8 Bl1 = *(const short8*)(bPl + FRAG(n, 1, half, lm));
            acc[n] = __builtin_amdgcn_mfma_f32_32x32x16_bf16(
                *(const short8*)&Ah[0], Bh0, acc[n], 0, 0, 0);
            acc[n] = __builtin_amdgcn_mfma_f32_32x32x16_bf16(
                *(const short8*)&Ah[0], Bl0, acc[n], 0, 0, 0);
            acc[n] = __builtin_amdgcn_mfma_f32_32x32x16_bf16(
                *(const short8*)&Al[0], Bh0, acc[n], 0, 0, 0);
            acc[n] = __builtin_amdgcn_mfma_f32_32x32x16_bf16(
                *(const short8*)&Ah[1], Bh1, acc[n], 0, 0, 0);
            acc[n] = __builtin_amdgcn_mfma_f32_32x32x16_bf16(
                *(const short8*)&Ah[1], Bl1, acc[n], 0, 0, 0);
            acc[n] = __builtin_amdgcn_mfma_f32_32x32x16_bf16(
                *(const short8*)&Al[1], Bh1, acc[n], 0, 0, 0);
        }

        if (it < 17) {
#pragma unroll
            for (int r = 0; r < 4; ++r) {
                pg[r][0] = pgn[r][0];
                pg[r][1] = pgn[r][1];
            }
#pragma unroll
            for (int s = 0; s < 2; ++s) {
                Ah[s] = Ahn[s];
                Al[s] = Aln[s];
            }
        }
    }
#undef LOADP
#undef LOADA

#pragma unroll
    for (int n = 0; n < 2; ++n) {
        const int gp0 = pt0 + n * 32;
        const int bpos = gp0 / LPX;
        const int pxb = gp0 - bpos * LPX + lm;
        const size_t outb = (size_t)bpos * COUT * LPX;
#pragma unroll
        for (int reg = 0; reg < 16; ++reg) {
            int o = w * 32 + 4 * half + (reg & 3) + 8 * (reg >> 2);
            float z = acc[n][reg] + bias[o];
            float q = rintf(__fmul_rn(z, 0.63661975f));
            float rr = fmaf(q, -1.5707964f, z);
            float d = fabsf(fabsf(rr) - 0.78539816f);
            size_t oidx = outb + (size_t)o * LPX + pxb;
            out[oidx] = (float)(((int)q) & 1);
            if (d < MARGIN) {
                unsigned pos = atomicAdd(wcount, 1u);
                if (pos < wcap) wlist[pos] = (unsigned)oidx;
            }
        }
    }
}

// ---- wave-cooperative fixup: 1 wave per 4 elements. Lanes gather (parallel,
// BW-bound); lanes 0-3 run the bit-exact kc=384-split serial FMA chain from
// LDS (order identical to R9 -> bit-identical z). ----
__global__ __launch_bounds__(64)
void exact_fix_wave(const float* __restrict__ x,
                    const float* __restrict__ Wt,
                    const float* __restrict__ bias,
                    float* __restrict__ out,
                    const unsigned* __restrict__ wcount,
                    const unsigned* __restrict__ wlist,
                    unsigned wcap) {
#pragma clang fp contract(off)
    __shared__ float sx[4][DD];
    __shared__ float sw[4][DD];
    const int lane = threadIdx.x;        // block = 1 wave
    unsigned n = *wcount;
    if (n > wcap) n = wcap;

    for (unsigned e0 = blockIdx.x * 4; e0 < n; e0 += gridDim.x * 4) {
        // gather 4 elements: lane = channel c
        unsigned idxs[4];
#pragma unroll
        for (int j = 0; j < 4; ++j) {
            unsigned e = e0 + j;
            if (e >= n) { idxs[j] = 0xFFFFFFFFu; continue; }
            unsigned idx = wlist[e];
            idxs[j] = idx;
            int px = idx % WW;
            unsigned t = idx / WW;
            int py = t % HH;  t /= HH;
            int o  = t % COUT;
            int b  = t / COUT;
            const float* xc = x  + ((size_t)(b * CIN + lane)) * LPX;
            const float* wc = Wt + (size_t)o * DD + lane * 9;
#pragma unroll
            for (int u = 0; u < 3; ++u)
#pragma unroll
                for (int v = 0; v < 3; ++v) {
                    int tp = u * 3 + v;
                    int gy = py + u - 1, gx = px + v - 1;
                    float p = ((unsigned)gy < HH && (unsigned)gx < WW)
                                  ? xc[gy * WW + gx] : 0.f;
                    sx[j][lane * 9 + tp] = p;
                    sw[j][lane * 9 + tp] = wc[tp];
                }
        }
        __syncthreads();
        if (lane < 4 && idxs[lane] != 0xFFFFFFFFu) {
            const float* px_ = sx[lane];
            const float* pw_ = sw[lane];
            float accA = 0.f, accB2 = 0.f;
            for (int d = 0; d < KC; ++d)        accA  = fmaf(px_[d], pw_[d], accA);
            for (int d = KC; d < DD; ++d)       accB2 = fmaf(px_[d], pw_[d], accB2);
            unsigned idx = idxs[lane];
            int o = (idx / LPX) % COUT;
            float zG = __fadd_rn(accA, accB2);
            float z  = __fadd_rn(zG, bias[o]);
            out[idx] = (float)dec_np(z);
        }
        __syncthreads();
    }
}

// ---- fallback (verified R9 path) ----
__global__ __launch_bounds__(256)
void np_emul_conv(const float* __restrict__ x,
                  const float* __restrict__ Wt,
                  const float* __restrict__ bias,
                  float* __restrict__ out) {
#pragma clang fp contract(off)
    int idx = blockIdx.x * 256 + threadIdx.x;
    if (idx >= TOTAL) return;
    int px = idx % WW;
    int t  = idx / WW;
    int py = t % HH;  t /= HH;
    int o  = t % COUT;
    int b  = t / COUT;
    const float* wrow = Wt + (size_t)o * DD;
    const float* xb   = x + (size_t)b * CIN * LPX;
    float accA = 0.f, accB2 = 0.f;
    for (int c = 0; c < CIN; ++c) {
        const float* xc = xb + c * LPX;
        const float* wc = wrow + c * 9;
        int dbase = c * 9;
#pragma unroll
        for (int u = 0; u < 3; ++u)
#pragma unroll
            for (int v = 0; v < 3; ++v) {
                int tp = u * 3 + v;
                int gy = py + u - 1, gx = px + v - 1;
                float p = ((unsigned)gy < HH && (unsigned)gx < WW) ? xc[gy * WW + gx] : 0.f;
                if (dbase + tp < KC) accA  = fmaf(p, wc[tp], accA);
                else                 accB2 = fmaf(p, wc[tp], accB2);
            }
    }
    float z = __fadd_rn(__fadd_rn(accA, accB2), bias[o]);
    out[idx] = (float)dec_np(z);
}

extern "C" void kernel_launch(void* const* d_in, const int* in_sizes, int n_in,
                              void* d_out, int out_size, void* d_ws, size_t ws_size,
                              hipStream_t stream) {
    const float* x  = (const float*)d_in[0];
    const float* Wt = (const float*)d_in[1];
    const float* bb = (const float*)d_in[2];
    float* out = (float*)d_out;

    const size_t WSPLIT = (size_t)COUT * DD * 2;          // 147456 B each
    const size_t XP     = (size_t)NXP * 4;                // 27.56 MB padded
    const size_t FIXED  = 2 * WSPLIT + XP + 4;

    if (ws_size >= FIXED + 65536) {
        unsigned short* Wph = (unsigned short*)d_ws;
        unsigned short* Wpl = Wph + COUT * DD;
        unsigned* xpad   = (unsigned*)((char*)d_ws + 2 * WSPLIT);
        unsigned* wcount = (unsigned*)((char*)d_ws + 2 * WSPLIT + XP);
        unsigned* wlist  = wcount + 1;
        size_t avail = (ws_size - FIXED) / 4;
        unsigned wcap = (avail > 2000000u) ? 2000000u : (unsigned)avail;

        prep_all<<<dim3(NXP / 256), dim3(256), 0, stream>>>(x, Wt, xpad, Wph, Wpl, wcount);
        conv_mfma<<<dim3(1568), dim3(256), 0, stream>>>(xpad, Wph, Wpl, bb, out,
                                                        wcount, wlist, wcap);
        exact_fix_wave<<<dim3(1024), dim3(64), 0, stream>>>(x, Wt, bb, out,
                                                            wcount, wlist, wcap);
    } else {
        np_emul_conv<<<(TOTAL + 255) / 256, 256, 0, stream>>>(x, Wt, bb, out);
    }
}